// Round 1
// baseline (306.988 us; speedup 1.0000x reference)
//
#include <hip/hip_runtime.h>
#include <math.h>

// Closed-form pipeline (see analysis):
//   Fx  = fft2_128(x)                          per (b,c) image, 256 images
//   FB  = fft2_256(pad+roll(k))                sparse 25x25 support
//   M   = (1 - S1) / (S2 + biaseps)            128x128 complex per image
//   FX  = Fx~ * (conj(FB)*M~ + D(u)D(v))       (biaseps cancels except in M)
//   out = real(ifft2_256(FX))
// D(u) = 1 + exp(-i*pi*u/128)

static __device__ __forceinline__ float2 cmul(float2 a, float2 b) {
    return make_float2(a.x * b.x - a.y * b.y, a.x * b.y + a.y * b.x);
}
static __device__ __forceinline__ float2 cadd(float2 a, float2 b) {
    return make_float2(a.x + b.x, a.y + b.y);
}

// ---------------- Stockham radix-2 FFT in LDS ----------------
// Row variant: blockDim == R * N/2 threads; each thread does 1 butterfly/stage.
// Returns index of buffer holding the result.
template <int N, int R, int SIGN>
static __device__ __forceinline__ int fft_lds_rows(float2 (&buf)[2][R][N]) {
    constexpr int HB = N / 2;
    const int tid = threadIdx.x;
    const int row = tid / HB;
    const int bt = tid % HB;
    int cur = 0, m = 1, sft = 0;
    for (int l = HB; l >= 1; l >>= 1) {
        __syncthreads();
        const int k = bt & (m - 1);
        const int j = bt >> sft;
        float s, c;
        __sincosf((float)SIGN * (float)M_PI * (float)j / (float)l, &s, &c);
        float2 a = buf[cur][row][bt];
        float2 b = buf[cur][row][bt + HB];
        float2 d = make_float2(a.x - b.x, a.y - b.y);
        float2 wd = make_float2(c * d.x - s * d.y, c * d.y + s * d.x);
        const int o = 2 * bt - k;
        buf[cur ^ 1][row][o] = make_float2(a.x + b.x, a.y + b.y);
        buf[cur ^ 1][row][o + m] = wd;
        cur ^= 1;
        m <<= 1;
        sft++;
    }
    __syncthreads();
    return cur;
}

// Column variant: TC independent columns, FFT along first LDS axis.
template <int N, int TC, int SIGN, int THREADS>
static __device__ __forceinline__ int fft_lds_cols(float2 (&buf)[2][N][TC]) {
    constexpr int HB = N / 2;
    constexpr int WORK = HB * TC;
    const int tid = threadIdx.x;
    int cur = 0, m = 1, sft = 0;
    for (int l = HB; l >= 1; l >>= 1) {
        __syncthreads();
        for (int w = tid; w < WORK; w += THREADS) {
            const int col = w % TC;
            const int bt = w / TC;
            const int k = bt & (m - 1);
            const int j = bt >> sft;
            float s, c;
            __sincosf((float)SIGN * (float)M_PI * (float)j / (float)l, &s, &c);
            float2 a = buf[cur][bt][col];
            float2 b = buf[cur][bt + HB][col];
            float2 d = make_float2(a.x - b.x, a.y - b.y);
            float2 wd = make_float2(c * d.x - s * d.y, c * d.y + s * d.x);
            const int o = 2 * bt - k;
            buf[cur ^ 1][o][col] = make_float2(a.x + b.x, a.y + b.y);
            buf[cur ^ 1][o + m][col] = wd;
        }
        cur ^= 1;
        m <<= 1;
        sft++;
    }
    __syncthreads();
    return cur;
}

// K1: row FFT of x (N=128), real input -> Fx rows. 4 rows/block.
__global__ __launch_bounds__(256) void k1_fft_rows_x(const float* __restrict__ x,
                                                     float2* __restrict__ Fx) {
    __shared__ float2 buf[2][4][128];
    const int tid = threadIdx.x;
    const int row = tid / 64;
    const int t = tid % 64;
    const int gr = blockIdx.x * 4 + row;  // img*128 + i
    const float2 xv = ((const float2*)x)[gr * 64 + t];
    buf[0][row][2 * t] = make_float2(xv.x, 0.f);
    buf[0][row][2 * t + 1] = make_float2(xv.y, 0.f);
    int cur = fft_lds_rows<128, 4, -1>(buf);
    float2* dst = Fx + gr * 128;
    dst[t] = buf[cur][row][t];
    dst[t + 64] = buf[cur][row][t + 64];
}

// K2: column FFT of Fx (N=128), in place. 8 cols/block.
__global__ __launch_bounds__(256) void k2_fft_cols_x(float2* __restrict__ Fx) {
    __shared__ float2 buf[2][128][8];
    const int tid = threadIdx.x;
    const int img = blockIdx.x >> 4;
    const int c0 = (blockIdx.x & 15) * 8;
    float2* base = Fx + img * (128 * 128) + c0;
    for (int it = 0; it < 4; ++it) {
        int idx = it * 256 + tid;
        buf[0][idx >> 3][idx & 7] = base[(idx >> 3) * 128 + (idx & 7)];
    }
    int cur = fft_lds_cols<128, 8, -1, 256>(buf);
    for (int it = 0; it < 4; ++it) {
        int idx = it * 256 + tid;
        base[(idx >> 3) * 128 + (idx & 7)] = buf[cur][idx >> 3][idx & 7];
    }
}

// K3: row FFT of padded+rolled psf (N=256) on the 25 nonzero rows only.
__global__ __launch_bounds__(128) void k3_fft_rows_k(const float* __restrict__ kin,
                                                     float2* __restrict__ FB) {
    __shared__ float2 buf[2][1][256];
    const int tid = threadIdx.x;  // 128
    const int img = blockIdx.x / 25;
    const int lr = blockIdx.x % 25;       // psf row index p
    const int u = (lr + 244) & 255;       // rolled row position
    const float* krow = kin + img * 625 + lr * 25;
    for (int h = 0; h < 2; ++h) {
        int v = tid + h * 128;
        int pc = (v + 12) & 255;
        buf[0][0][v] = make_float2(pc < 25 ? krow[pc] : 0.f, 0.f);
    }
    int cur = fft_lds_rows<256, 1, -1>(buf);
    float2* dst = FB + img * 65536 + u * 256;
    dst[tid] = buf[cur][0][tid];
    dst[tid + 128] = buf[cur][0][tid + 128];
}

// K4: column FFT of FB (N=256); only 25 rows are nonzero on input. In place.
__global__ __launch_bounds__(256) void k4_fft_cols_k(float2* __restrict__ FB) {
    __shared__ float2 buf[2][256][8];
    const int tid = threadIdx.x;
    const int img = blockIdx.x >> 5;
    const int c0 = (blockIdx.x & 31) * 8;
    float2* base = FB + img * 65536 + c0;
    for (int it = 0; it < 8; ++it) {
        int idx = it * 256 + tid;
        buf[0][idx >> 3][idx & 7] = make_float2(0.f, 0.f);
    }
    __syncthreads();
    if (tid < 200) {
        int lr = tid >> 3, c = tid & 7;
        int u = (lr + 244) & 255;
        buf[0][u][c] = base[u * 256 + c];
    }
    int cur = fft_lds_cols<256, 8, -1, 256>(buf);
    for (int it = 0; it < 8; ++it) {
        int idx = it * 256 + tid;
        base[(idx >> 3) * 256 + (idx & 7)] = buf[cur][idx >> 3][idx & 7];
    }
}

// K5: M = (1 - S1) / (S2 + biaseps), 128x128 complex per image.
__global__ __launch_bounds__(256) void k5_build_M(const float2* __restrict__ FB,
                                                  const float* __restrict__ alpha,
                                                  float2* __restrict__ M) {
    const int flat = blockIdx.x * 256 + threadIdx.x;
    const int img = flat >> 14;
    const int ij = flat & 16383;
    const int i = ij >> 7, j = ij & 127;
    const float2* Fb = FB + img * 65536;
    float2 f00 = Fb[i * 256 + j];
    float2 f01 = Fb[i * 256 + j + 128];
    float2 f10 = Fb[(i + 128) * 256 + j];
    float2 f11 = Fb[(i + 128) * 256 + j + 128];
    float si, ci, sj, cj;
    __sincosf(-(float)M_PI * (float)i / 128.f, &si, &ci);
    __sincosf(-(float)M_PI * (float)j / 128.f, &sj, &cj);
    float2 Di0 = make_float2(1.f + ci, si);
    float2 Di1 = make_float2(1.f - ci, -si);
    float2 Dj0 = make_float2(1.f + cj, sj);
    float2 Dj1 = make_float2(1.f - cj, -sj);
    float2 S1 = cadd(cadd(cmul(cmul(f00, Di0), Dj0), cmul(cmul(f10, Di1), Dj0)),
                     cadd(cmul(cmul(f01, Di0), Dj1), cmul(cmul(f11, Di1), Dj1)));
    S1.x *= 0.25f;
    S1.y *= 0.25f;
    float S2 = 0.25f * (f00.x * f00.x + f00.y * f00.y + f01.x * f01.x + f01.y * f01.y +
                        f10.x * f10.x + f10.y * f10.y + f11.x * f11.x + f11.y * f11.y);
    float b = 1.f / (1.f + __expf(9.f - alpha[img & 63])) + 1e-3f;
    float inv = 1.f / (S2 + b);
    M[img * 16384 + ij] = make_float2((1.f - S1.x) * inv, (-S1.y) * inv);
}

// K6: build FX and inverse row FFT (N=256), in place over FB. 2 rows/block.
__global__ __launch_bounds__(256) void k6_fx_rowifft(float2* __restrict__ FB,
                                                     const float2* __restrict__ Fx,
                                                     const float2* __restrict__ M) {
    __shared__ float2 buf[2][2][256];
    const int tid = threadIdx.x;
    const int img = blockIdx.x >> 7;
    const int u = (blockIdx.x & 127) * 2 + (tid >> 7);
    const int row = tid >> 7;
    const int t = tid & 127;
    const int um = u & 127;
    float2* fbrow = FB + img * 65536 + u * 256;
    float2 fb0 = fbrow[t];
    float2 fb1 = fbrow[t + 128];
    float2 fx = Fx[img * 16384 + um * 128 + t];
    float2 mm = M[img * 16384 + um * 128 + t];
    float su, cu, sv, cv;
    __sincosf(-(float)M_PI * (float)um / 128.f, &su, &cu);
    __sincosf(-(float)M_PI * (float)t / 128.f, &sv, &cv);
    float2 Du = (u < 128) ? make_float2(1.f + cu, su) : make_float2(1.f - cu, -su);
    float2 Dv0 = make_float2(1.f + cv, sv);
    float2 Dv1 = make_float2(1.f - cv, -sv);
    const float scale = 1.f / 65536.f;  // ifft2 normalization, applied once
    float2 cj0 = make_float2(fb0.x, -fb0.y);
    float2 cj1 = make_float2(fb1.x, -fb1.y);
    float2 t0 = cadd(cmul(cj0, mm), cmul(Du, Dv0));
    float2 t1 = cadd(cmul(cj1, mm), cmul(Du, Dv1));
    float2 FX0 = cmul(fx, t0);
    float2 FX1 = cmul(fx, t1);
    buf[0][row][t] = make_float2(FX0.x * scale, FX0.y * scale);
    buf[0][row][t + 128] = make_float2(FX1.x * scale, FX1.y * scale);
    int cur = fft_lds_rows<256, 2, 1>(buf);
    fbrow[t] = buf[cur][row][t];
    fbrow[t + 128] = buf[cur][row][t + 128];
}

// K7: inverse column FFT (N=256), write real part to out.
__global__ __launch_bounds__(256) void k7_colifft_out(const float2* __restrict__ FB,
                                                      float* __restrict__ out) {
    __shared__ float2 buf[2][256][8];
    const int tid = threadIdx.x;
    const int img = blockIdx.x >> 5;
    const int c0 = (blockIdx.x & 31) * 8;
    const float2* base = FB + img * 65536 + c0;
    for (int it = 0; it < 8; ++it) {
        int idx = it * 256 + tid;
        buf[0][idx >> 3][idx & 7] = base[(idx >> 3) * 256 + (idx & 7)];
    }
    int cur = fft_lds_cols<256, 8, 1, 256>(buf);
    float* obase = out + img * 65536 + c0;
    for (int it = 0; it < 8; ++it) {
        int idx = it * 256 + tid;
        obase[(idx >> 3) * 256 + (idx & 7)] = buf[cur][idx >> 3][idx & 7].x;
    }
}

extern "C" void kernel_launch(void* const* d_in, const int* in_sizes, int n_in,
                              void* d_out, int out_size, void* d_ws, size_t ws_size,
                              hipStream_t stream) {
    const float* x = (const float*)d_in[0];      // (4,64,128,128)
    const float* k = (const float*)d_in[1];      // (4,64,25,25)
    const float* alpha = (const float*)d_in[2];  // (1,64,1,1)
    float* out = (float*)d_out;                  // (4,64,256,256)

    float2* Fx = (float2*)d_ws;        // 256 * 128*128 complex = 32 MB
    float2* FB = Fx + 256 * 16384;     // 256 * 256*256 complex = 128 MB
    float2* M = FB + 256 * 65536;      // 256 * 128*128 complex = 32 MB

    hipLaunchKernelGGL(k1_fft_rows_x, dim3(8192), dim3(256), 0, stream, x, Fx);
    hipLaunchKernelGGL(k2_fft_cols_x, dim3(4096), dim3(256), 0, stream, Fx);
    hipLaunchKernelGGL(k3_fft_rows_k, dim3(6400), dim3(128), 0, stream, k, FB);
    hipLaunchKernelGGL(k4_fft_cols_k, dim3(8192), dim3(256), 0, stream, FB);
    hipLaunchKernelGGL(k5_build_M, dim3(16384), dim3(256), 0, stream, FB, alpha, M);
    hipLaunchKernelGGL(k6_fx_rowifft, dim3(32768), dim3(256), 0, stream, FB, Fx, M);
    hipLaunchKernelGGL(k7_colifft_out, dim3(8192), dim3(256), 0, stream, FB, out);
}

// Round 2
// 274.939 us; speedup vs baseline: 1.1166x; 1.1166x over previous
//
#include <hip/hip_runtime.h>
#include <math.h>

// Closed-form pipeline with Hermitian (real-output) symmetry:
//   Fx  = fft2_128(x)                        per (b,c) image, 256 images
//   FBh = fft2_256(pad+roll(k)) rows 0..128  (Hermitian: rest is conj-flip)
//   K6 fused: M = (1-S1)/(S2+b) in registers; FX row built from FBh rows
//             {um, 128-um}; row IFFT; write Z rows 0..128 only
//   K7: C2R column IFFT via 128-pt complex FFT (Y-fold), write real out
// D(u) = 1 + exp(-i*pi*u/128); biaseps cancels except inside M.

static __device__ __forceinline__ float2 cmul(float2 a, float2 b) {
    return make_float2(a.x * b.x - a.y * b.y, a.x * b.y + a.y * b.x);
}
static __device__ __forceinline__ float2 cadd(float2 a, float2 b) {
    return make_float2(a.x + b.x, a.y + b.y);
}
static __device__ __forceinline__ float2 csub(float2 a, float2 b) {
    return make_float2(a.x - b.x, a.y - b.y);
}
static __device__ __forceinline__ float2 conjf2(float2 a) {
    return make_float2(a.x, -a.y);
}

// ---------------- Stockham radix-2 FFT in LDS ----------------
template <int N, int R, int SIGN>
static __device__ __forceinline__ int fft_lds_rows(float2 (&buf)[2][R][N]) {
    constexpr int HB = N / 2;
    const int tid = threadIdx.x;
    const int row = tid / HB;
    const int bt = tid % HB;
    int cur = 0, m = 1, sft = 0;
    for (int l = HB; l >= 1; l >>= 1) {
        __syncthreads();
        const int k = bt & (m - 1);
        const int j = bt >> sft;
        float s, c;
        __sincosf((float)SIGN * (float)M_PI * (float)j / (float)l, &s, &c);
        float2 a = buf[cur][row][bt];
        float2 b = buf[cur][row][bt + HB];
        float2 d = make_float2(a.x - b.x, a.y - b.y);
        float2 wd = make_float2(c * d.x - s * d.y, c * d.y + s * d.x);
        const int o = 2 * bt - k;
        buf[cur ^ 1][row][o] = make_float2(a.x + b.x, a.y + b.y);
        buf[cur ^ 1][row][o + m] = wd;
        cur ^= 1;
        m <<= 1;
        sft++;
    }
    __syncthreads();
    return cur;
}

template <int N, int TC, int TCP, int SIGN, int THREADS>
static __device__ __forceinline__ int fft_lds_cols(float2 (&buf)[2][N][TCP]) {
    constexpr int HB = N / 2;
    constexpr int WORK = HB * TC;
    const int tid = threadIdx.x;
    int cur = 0, m = 1, sft = 0;
    for (int l = HB; l >= 1; l >>= 1) {
        __syncthreads();
        for (int w = tid; w < WORK; w += THREADS) {
            const int col = w % TC;
            const int bt = w / TC;
            const int k = bt & (m - 1);
            const int j = bt >> sft;
            float s, c;
            __sincosf((float)SIGN * (float)M_PI * (float)j / (float)l, &s, &c);
            float2 a = buf[cur][bt][col];
            float2 b = buf[cur][bt + HB][col];
            float2 d = make_float2(a.x - b.x, a.y - b.y);
            float2 wd = make_float2(c * d.x - s * d.y, c * d.y + s * d.x);
            const int o = 2 * bt - k;
            buf[cur ^ 1][o][col] = make_float2(a.x + b.x, a.y + b.y);
            buf[cur ^ 1][o + m][col] = wd;
        }
        cur ^= 1;
        m <<= 1;
        sft++;
    }
    __syncthreads();
    return cur;
}

// K1: row FFT of x (N=128), real input -> Fx rows. 4 rows/block.
__global__ __launch_bounds__(256) void k1_fft_rows_x(const float* __restrict__ x,
                                                     float2* __restrict__ Fx) {
    __shared__ float2 buf[2][4][128];
    const int tid = threadIdx.x;
    const int row = tid / 64;
    const int t = tid % 64;
    const int gr = blockIdx.x * 4 + row;  // img*128 + i
    const float2 xv = ((const float2*)x)[gr * 64 + t];
    buf[0][row][2 * t] = make_float2(xv.x, 0.f);
    buf[0][row][2 * t + 1] = make_float2(xv.y, 0.f);
    int cur = fft_lds_rows<128, 4, -1>(buf);
    float2* dst = Fx + gr * 128;
    dst[t] = buf[cur][row][t];
    dst[t + 64] = buf[cur][row][t + 64];
}

// K2: column FFT of Fx (N=128), in place. 8 cols/block (padded LDS).
__global__ __launch_bounds__(256) void k2_fft_cols_x(float2* __restrict__ Fx) {
    __shared__ float2 buf[2][128][9];
    const int tid = threadIdx.x;
    const int img = blockIdx.x >> 4;
    const int c0 = (blockIdx.x & 15) * 8;
    float2* base = Fx + img * (128 * 128) + c0;
    for (int it = 0; it < 4; ++it) {
        int idx = it * 256 + tid;
        buf[0][idx >> 3][idx & 7] = base[(idx >> 3) * 128 + (idx & 7)];
    }
    int cur = fft_lds_cols<128, 8, 9, -1, 256>(buf);
    for (int it = 0; it < 4; ++it) {
        int idx = it * 256 + tid;
        base[(idx >> 3) * 128 + (idx & 7)] = buf[cur][idx >> 3][idx & 7];
    }
}

// K3: row FFT of padded+rolled psf (N=256), compact output [img][25][256].
__global__ __launch_bounds__(128) void k3_fft_rows_k(const float* __restrict__ kin,
                                                     float2* __restrict__ FBtmp) {
    __shared__ float2 buf[2][1][256];
    const int tid = threadIdx.x;  // 128
    const int img = blockIdx.x / 25;
    const int lr = blockIdx.x % 25;  // psf row index p
    const float* krow = kin + img * 625 + lr * 25;
    for (int h = 0; h < 2; ++h) {
        int v = tid + h * 128;
        int pc = (v + 12) & 255;
        buf[0][0][v] = make_float2(pc < 25 ? krow[pc] : 0.f, 0.f);
    }
    int cur = fft_lds_rows<256, 1, -1>(buf);
    float2* dst = FBtmp + img * 6400 + lr * 256;
    dst[tid] = buf[cur][0][tid];
    dst[tid + 128] = buf[cur][0][tid + 128];
}

// K4: column FFT of FB (N=256) from compact 25 rows; store rows 0..128 only.
__global__ __launch_bounds__(256) void k4_fft_cols_k(const float2* __restrict__ FBtmp,
                                                     float2* __restrict__ FBh) {
    __shared__ float2 buf[2][256][9];
    const int tid = threadIdx.x;
    const int img = blockIdx.x >> 5;
    const int c0 = (blockIdx.x & 31) * 8;
    for (int it = 0; it < 8; ++it) {
        int idx = it * 256 + tid;
        buf[0][idx >> 3][idx & 7] = make_float2(0.f, 0.f);
    }
    __syncthreads();
    if (tid < 200) {
        int lr = tid >> 3, c = tid & 7;
        int u = (lr + 244) & 255;  // rolled row position
        buf[0][u][c] = FBtmp[img * 6400 + lr * 256 + c0 + c];
    }
    int cur = fft_lds_cols<256, 8, 9, -1, 256>(buf);
    float2* dst = FBh + img * 33024 + c0;
    for (int idx = tid; idx < 129 * 8; idx += 256) {
        int r = idx >> 3, c = idx & 7;
        dst[r * 256 + c] = buf[cur][r][c];
    }
}

// K6: fused M + FX build + row IFFT. Row tasks u = 0..128 per image (2/block).
__global__ __launch_bounds__(256) void k6_fused(const float2* __restrict__ FBh,
                                                const float2* __restrict__ Fx,
                                                const float* __restrict__ alpha,
                                                float2* __restrict__ Z) {
    __shared__ float2 buf[2][2][256];
    const int tid = threadIdx.x;
    const int row = tid >> 7;
    const int t = tid & 127;
    const int img = blockIdx.x / 65;
    const int p = blockIdx.x % 65;
    const int u = p * 2 + row;        // 0..129 (129 is a dummy duplicate)
    const int uc = (u < 128) ? u : 128;
    const bool wr = (u <= 128);
    const int um = uc & 127;          // 0..127 (u=128 -> 0)
    const float2* base = FBh + img * 33024;

    // FB[um, t], FB[um, t+128] (self-needed values only -> registers)
    float2 f00 = base[um * 256 + t];
    float2 f01 = base[um * 256 + t + 128];
    // FB[um+128, t], FB[um+128, t+128] via Hermitian conj-flip of row 128-um
    float2 f10, f11;
    if (um == 0) {
        f10 = base[128 * 256 + t];
        f11 = base[128 * 256 + t + 128];
    } else {
        int rs = (128 - um) * 256;
        f10 = conjf2(base[rs + ((256 - t) & 255)]);
        f11 = conjf2(base[rs + (128 - t)]);
    }
    float2 fx = Fx[img * 16384 + um * 128 + t];

    // M[um, t] = (1 - S1)/(S2 + biaseps)   -- all inputs per-thread
    float si, ci, sj, cj;
    __sincosf(-(float)M_PI * (float)um / 128.f, &si, &ci);
    __sincosf(-(float)M_PI * (float)t / 128.f, &sj, &cj);
    float2 Di0 = make_float2(1.f + ci, si);
    float2 Di1 = make_float2(1.f - ci, -si);
    float2 Dj0 = make_float2(1.f + cj, sj);
    float2 Dj1 = make_float2(1.f - cj, -sj);
    float2 S1 = cadd(cadd(cmul(cmul(f00, Di0), Dj0), cmul(cmul(f10, Di1), Dj0)),
                     cadd(cmul(cmul(f01, Di0), Dj1), cmul(cmul(f11, Di1), Dj1)));
    S1.x *= 0.25f;
    S1.y *= 0.25f;
    float S2 = 0.25f * (f00.x * f00.x + f00.y * f00.y + f01.x * f01.x + f01.y * f01.y +
                        f10.x * f10.x + f10.y * f10.y + f11.x * f11.x + f11.y * f11.y);
    float b = 1.f / (1.f + __expf(9.f - alpha[img & 63])) + 1e-3f;
    float inv = 1.f / (S2 + b);
    float2 mm = make_float2((1.f - S1.x) * inv, (-S1.y) * inv);

    // FX[u, t] and FX[u, t+128]; C-row is FB[u,:] = (u<128 ? row um : row 128)
    float2 c0v = (uc < 128) ? f00 : f10;
    float2 c1v = (uc < 128) ? f01 : f11;
    float2 Du = (uc < 128) ? make_float2(1.f + ci, si) : make_float2(1.f - ci, -si);
    float2 Dv0 = make_float2(1.f + cj, sj);
    float2 Dv1 = make_float2(1.f - cj, -sj);
    const float scale = 1.f / 65536.f;
    float2 t0 = cadd(cmul(conjf2(c0v), mm), cmul(Du, Dv0));
    float2 t1 = cadd(cmul(conjf2(c1v), mm), cmul(Du, Dv1));
    float2 FX0 = cmul(fx, t0);
    float2 FX1 = cmul(fx, t1);
    buf[0][row][t] = make_float2(FX0.x * scale, FX0.y * scale);
    buf[0][row][t + 128] = make_float2(FX1.x * scale, FX1.y * scale);
    int cur = fft_lds_rows<256, 2, 1>(buf);
    if (wr) {
        float2* zb = Z + img * 33024 + u * 256;
        zb[t] = buf[cur][row][t];
        zb[t + 128] = buf[cur][row][t + 128];
    }
}

// K7: C2R column IFFT. S = Z rows 0..128; Y-fold -> 128-pt complex IFFT;
// out[2n,j] = Re y[n], out[2n+1,j] = Im y[n].
__global__ __launch_bounds__(256) void k7_c2r(const float2* __restrict__ Z,
                                              float* __restrict__ out) {
    __shared__ float2 S[129][9];
    __shared__ float2 buf[2][128][9];
    const int tid = threadIdx.x;
    const int img = blockIdx.x >> 5;
    const int c0 = (blockIdx.x & 31) * 8;
    const float2* zb = Z + img * 33024 + c0;
    for (int idx = tid; idx < 129 * 8; idx += 256) {
        int r = idx >> 3, c = idx & 7;
        S[r][c] = zb[r * 256 + c];
    }
    __syncthreads();
    for (int idx = tid; idx < 128 * 8; idx += 256) {
        int u = idx >> 3, c = idx & 7;
        float2 su = S[u][c];
        float2 s2 = conjf2(S[128 - u][c]);  // S[u+128] via Hermitian
        float2 e = cadd(su, s2);
        float2 o = csub(su, s2);
        float ws_, wc_;
        __sincosf((float)M_PI * (float)u / 128.f, &ws_, &wc_);
        float2 wo = make_float2(wc_ * o.x - ws_ * o.y, wc_ * o.y + ws_ * o.x);
        buf[0][u][c] = make_float2(e.x - wo.y, e.y + wo.x);  // e + i*wo
    }
    int cur = fft_lds_cols<128, 8, 9, 1, 256>(buf);
    float* ob = out + img * 65536 + c0;
    for (int idx = tid; idx < 128 * 8; idx += 256) {
        int n = idx >> 3, c = idx & 7;
        float2 y = buf[cur][n][c];
        ob[(2 * n) * 256 + c] = y.x;
        ob[(2 * n + 1) * 256 + c] = y.y;
    }
}

extern "C" void kernel_launch(void* const* d_in, const int* in_sizes, int n_in,
                              void* d_out, int out_size, void* d_ws, size_t ws_size,
                              hipStream_t stream) {
    const float* x = (const float*)d_in[0];      // (4,64,128,128)
    const float* k = (const float*)d_in[1];      // (4,64,25,25)
    const float* alpha = (const float*)d_in[2];  // (1,64,1,1)
    float* out = (float*)d_out;                  // (4,64,256,256)

    float2* Fx = (float2*)d_ws;           // 256*16384   = 32 MB
    float2* FBh = Fx + 256 * 16384;       // 256*129*256 = 67.6 MB
    float2* Z = FBh + 256 * 33024;        // 256*129*256 = 67.6 MB
    float2* FBtmp = Z + 256 * 33024;      // 256*25*256  = 13.1 MB

    hipLaunchKernelGGL(k1_fft_rows_x, dim3(8192), dim3(256), 0, stream, x, Fx);
    hipLaunchKernelGGL(k2_fft_cols_x, dim3(4096), dim3(256), 0, stream, Fx);
    hipLaunchKernelGGL(k3_fft_rows_k, dim3(6400), dim3(128), 0, stream, k, FBtmp);
    hipLaunchKernelGGL(k4_fft_cols_k, dim3(8192), dim3(256), 0, stream, FBtmp, FBh);
    hipLaunchKernelGGL(k6_fused, dim3(256 * 65), dim3(256), 0, stream, FBh, Fx, alpha, Z);
    hipLaunchKernelGGL(k7_c2r, dim3(8192), dim3(256), 0, stream, Z, out);
}

// Round 4
// 253.306 us; speedup vs baseline: 1.2119x; 1.0854x over previous
//
#include <hip/hip_runtime.h>
#include <math.h>

// Closed-form pipeline with Hermitian (real-output) symmetry:
//   Fx  = fft2_128(x)                 (k1 rows pack-2 real trick, k2 cols)
//   FBh = fft2_256(pad+roll(k)) rows 0..128
//         (k3: row FFT of 25 psf rows; k4: DIRECT 25-term column DFT)
//   k6 fused: M=(1-S1)/(S2+b) in regs; FX built from FBh rows {um,128-um};
//             row IFFT; write Z rows 0..128 only
//   k7: C2R column IFFT via 128-pt complex FFT fold
// LDS layout rule (R2 post-mortem): float2 column tiles use width 16
// (128 B = full bank row) -> bank-pair == col, conflict-free at every stage.
// R3 post-mortem: LDS tiles larger than blockDim must be loaded with a
// grid-stride loop (k4's S[25][16]=400 entries > 256 threads).

static __device__ __forceinline__ float2 cmul(float2 a, float2 b) {
    return make_float2(a.x * b.x - a.y * b.y, a.x * b.y + a.y * b.x);
}
static __device__ __forceinline__ float2 cadd(float2 a, float2 b) {
    return make_float2(a.x + b.x, a.y + b.y);
}
static __device__ __forceinline__ float2 csub(float2 a, float2 b) {
    return make_float2(a.x - b.x, a.y - b.y);
}
static __device__ __forceinline__ float2 conjf2(float2 a) {
    return make_float2(a.x, -a.y);
}

// ---------------- Stockham radix-2 FFT in LDS ----------------
template <int N, int R, int SIGN>
static __device__ __forceinline__ int fft_lds_rows(float2 (&buf)[2][R][N]) {
    constexpr int HB = N / 2;
    const int tid = threadIdx.x;
    const int row = tid / HB;
    const int bt = tid % HB;
    int cur = 0, m = 1, sft = 0;
    for (int l = HB; l >= 1; l >>= 1) {
        __syncthreads();
        const int k = bt & (m - 1);
        const int j = bt >> sft;
        float s, c;
        __sincosf((float)SIGN * (float)M_PI * (float)j / (float)l, &s, &c);
        float2 a = buf[cur][row][bt];
        float2 b = buf[cur][row][bt + HB];
        float2 d = make_float2(a.x - b.x, a.y - b.y);
        float2 wd = make_float2(c * d.x - s * d.y, c * d.y + s * d.x);
        const int o = 2 * bt - k;
        buf[cur ^ 1][row][o] = make_float2(a.x + b.x, a.y + b.y);
        buf[cur ^ 1][row][o + m] = wd;
        cur ^= 1;
        m <<= 1;
        sft++;
    }
    __syncthreads();
    return cur;
}

// Column variant: TC columns (use TC=16 -> conflict-free), FFT along axis 0.
template <int N, int TC, int SIGN, int THREADS>
static __device__ __forceinline__ int fft_lds_cols(float2 (&buf)[2][N][TC]) {
    constexpr int HB = N / 2;
    constexpr int WORK = HB * TC;
    const int tid = threadIdx.x;
    int cur = 0, m = 1, sft = 0;
    for (int l = HB; l >= 1; l >>= 1) {
        __syncthreads();
        for (int w = tid; w < WORK; w += THREADS) {
            const int col = w % TC;
            const int bt = w / TC;
            const int k = bt & (m - 1);
            const int j = bt >> sft;
            float s, c;
            __sincosf((float)SIGN * (float)M_PI * (float)j / (float)l, &s, &c);
            float2 a = buf[cur][bt][col];
            float2 b = buf[cur][bt + HB][col];
            float2 d = make_float2(a.x - b.x, a.y - b.y);
            float2 wd = make_float2(c * d.x - s * d.y, c * d.y + s * d.x);
            const int o = 2 * bt - k;
            buf[cur ^ 1][o][col] = make_float2(a.x + b.x, a.y + b.y);
            buf[cur ^ 1][o + m][col] = wd;
        }
        cur ^= 1;
        m <<= 1;
        sft++;
    }
    __syncthreads();
    return cur;
}

// K1: row FFT of x (N=128) with pack-2: rows (2r,2r+1) as re+i*im of one FFT.
__global__ __launch_bounds__(256) void k1_fft_rows_x(const float* __restrict__ x,
                                                     float2* __restrict__ Fx) {
    __shared__ float2 buf[2][4][128];
    const int tid = threadIdx.x;
    const int row = tid >> 6;   // pair slot 0..3
    const int t = tid & 63;
    const int gpair = blockIdx.x * 4 + row;  // img*64 + pr
    const float* r0 = x + (size_t)gpair * 256;        // row 2*pr (128 floats)
    const float* r1 = r0 + 128;                       // row 2*pr+1
    const float2 a0 = ((const float2*)r0)[t];
    const float2 a1 = ((const float2*)r1)[t];
    buf[0][row][2 * t].x = a0.x;
    buf[0][row][2 * t].y = a1.x;
    buf[0][row][2 * t + 1].x = a0.y;
    buf[0][row][2 * t + 1].y = a1.y;
    int cur = fft_lds_rows<128, 4, -1>(buf);
    float2* d0 = Fx + (size_t)gpair * 256;            // Fx row 2*pr
    float2* d1 = d0 + 128;
    for (int h = 0; h < 2; ++h) {
        int tt = t + h * 64;
        float2 Zt = buf[cur][row][tt];
        float2 Zm = buf[cur][row][(128 - tt) & 127];
        d0[tt] = make_float2(0.5f * (Zt.x + Zm.x), 0.5f * (Zt.y - Zm.y));
        float ax = Zt.x - Zm.x, ay = Zt.y + Zm.y;
        d1[tt] = make_float2(0.5f * ay, -0.5f * ax);
    }
}

// K2: column FFT of Fx (N=128), in place. 16 cols/block (conflict-free).
__global__ __launch_bounds__(256) void k2_fft_cols_x(float2* __restrict__ Fx) {
    __shared__ float2 buf[2][128][16];
    const int tid = threadIdx.x;
    const int img = blockIdx.x >> 3;
    const int c0 = (blockIdx.x & 7) * 16;
    float2* base = Fx + (size_t)img * 16384 + c0;
    for (int it = 0; it < 8; ++it) {
        int idx = it * 256 + tid;
        buf[0][idx >> 4][idx & 15] = base[(idx >> 4) * 128 + (idx & 15)];
    }
    int cur = fft_lds_cols<128, 16, -1, 256>(buf);
    for (int it = 0; it < 8; ++it) {
        int idx = it * 256 + tid;
        base[(idx >> 4) * 128 + (idx & 15)] = buf[cur][idx >> 4][idx & 15];
    }
}

// K3: row FFT of padded+rolled psf (N=256), compact output [img][25][256].
__global__ __launch_bounds__(128) void k3_fft_rows_k(const float* __restrict__ kin,
                                                     float2* __restrict__ FBtmp) {
    __shared__ float2 buf[2][1][256];
    const int tid = threadIdx.x;  // 128
    const int img = blockIdx.x / 25;
    const int lr = blockIdx.x % 25;
    const float* krow = kin + img * 625 + lr * 25;
    for (int h = 0; h < 2; ++h) {
        int v = tid + h * 128;
        int pc = (v + 12) & 255;
        buf[0][0][v] = make_float2(pc < 25 ? krow[pc] : 0.f, 0.f);
    }
    int cur = fft_lds_rows<256, 1, -1>(buf);
    float2* dst = FBtmp + (size_t)img * 6400 + lr * 256;
    dst[tid] = buf[cur][0][tid];
    dst[tid + 128] = buf[cur][0][tid + 128];
}

// K4: direct column DFT (25 nonzero rows) -> FBh rows 0..128.
// FB[u][j] = sum_p FBtmp[p][j] * W^(u*(p+244)),  W = exp(-2*pi*i/256).
__global__ __launch_bounds__(256) void k4_dft_cols_k(const float2* __restrict__ FBtmp,
                                                     float2* __restrict__ FBh) {
    __shared__ float2 T[256];
    __shared__ float2 S[25][16];
    const int tid = threadIdx.x;
    const int img = blockIdx.x >> 4;
    const int c0 = (blockIdx.x & 15) * 16;
    {
        float s, c;
        __sincosf(-2.f * (float)M_PI * (float)tid / 256.f, &s, &c);
        T[tid] = make_float2(c, s);
    }
    // R3 bug fix: 400 entries > 256 threads -> must loop.
    for (int idx = tid; idx < 25 * 16; idx += 256) {
        int p = idx >> 4, c = idx & 15;
        S[p][c] = FBtmp[(size_t)img * 6400 + p * 256 + c0 + c];
    }
    __syncthreads();
    const int c = tid & 15;
    const int ur = tid >> 4;
    float2* dst = FBh + (size_t)img * 33024 + c0 + c;
    for (int u = ur; u <= 128; u += 16) {
        int n = (u * 244) & 255;
        float2 acc = make_float2(0.f, 0.f);
#pragma unroll
        for (int p = 0; p < 25; ++p) {
            float2 tw = T[n];
            float2 sv = S[p][c];
            acc.x += tw.x * sv.x - tw.y * sv.y;
            acc.y += tw.x * sv.y + tw.y * sv.x;
            n = (n + u) & 255;
        }
        dst[(size_t)u * 256] = acc;
    }
}

// K6: fused M + FX build + row IFFT. Row tasks u = 0..128 per image (2/block).
__global__ __launch_bounds__(256) void k6_fused(const float2* __restrict__ FBh,
                                                const float2* __restrict__ Fx,
                                                const float* __restrict__ alpha,
                                                float2* __restrict__ Z) {
    __shared__ float2 buf[2][2][256];
    const int tid = threadIdx.x;
    const int row = tid >> 7;
    const int t = tid & 127;
    const int img = blockIdx.x / 65;
    const int p = blockIdx.x % 65;
    const int u = p * 2 + row;        // 0..129 (129 = dummy duplicate)
    const int uc = (u < 128) ? u : 128;
    const bool wr = (u <= 128);
    const int um = uc & 127;
    const float2* base = FBh + (size_t)img * 33024;

    float2 f00 = base[um * 256 + t];
    float2 f01 = base[um * 256 + t + 128];
    float2 f10, f11;
    if (um == 0) {
        f10 = base[128 * 256 + t];
        f11 = base[128 * 256 + t + 128];
    } else {
        int rs = (128 - um) * 256;
        f10 = conjf2(base[rs + ((256 - t) & 255)]);
        f11 = conjf2(base[rs + (128 - t)]);
    }
    float2 fx = Fx[(size_t)img * 16384 + um * 128 + t];

    float si, ci, sj, cj;
    __sincosf(-(float)M_PI * (float)um / 128.f, &si, &ci);
    __sincosf(-(float)M_PI * (float)t / 128.f, &sj, &cj);
    float2 Di0 = make_float2(1.f + ci, si);
    float2 Di1 = make_float2(1.f - ci, -si);
    float2 Dj0 = make_float2(1.f + cj, sj);
    float2 Dj1 = make_float2(1.f - cj, -sj);
    float2 S1 = cadd(cadd(cmul(cmul(f00, Di0), Dj0), cmul(cmul(f10, Di1), Dj0)),
                     cadd(cmul(cmul(f01, Di0), Dj1), cmul(cmul(f11, Di1), Dj1)));
    S1.x *= 0.25f;
    S1.y *= 0.25f;
    float S2 = 0.25f * (f00.x * f00.x + f00.y * f00.y + f01.x * f01.x + f01.y * f01.y +
                        f10.x * f10.x + f10.y * f10.y + f11.x * f11.x + f11.y * f11.y);
    float b = 1.f / (1.f + __expf(9.f - alpha[img & 63])) + 1e-3f;
    float inv = 1.f / (S2 + b);
    float2 mm = make_float2((1.f - S1.x) * inv, (-S1.y) * inv);

    float2 c0v = (uc < 128) ? f00 : f10;
    float2 c1v = (uc < 128) ? f01 : f11;
    float2 Du = (uc < 128) ? make_float2(1.f + ci, si) : make_float2(1.f - ci, -si);
    float2 Dv0 = make_float2(1.f + cj, sj);
    float2 Dv1 = make_float2(1.f - cj, -sj);
    const float scale = 1.f / 65536.f;
    float2 t0 = cadd(cmul(conjf2(c0v), mm), cmul(Du, Dv0));
    float2 t1 = cadd(cmul(conjf2(c1v), mm), cmul(Du, Dv1));
    float2 FX0 = cmul(fx, t0);
    float2 FX1 = cmul(fx, t1);
    buf[0][row][t] = make_float2(FX0.x * scale, FX0.y * scale);
    buf[0][row][t + 128] = make_float2(FX1.x * scale, FX1.y * scale);
    int cur = fft_lds_rows<256, 2, 1>(buf);
    if (wr) {
        float2* zb = Z + (size_t)img * 33024 + u * 256;
        zb[t] = buf[cur][row][t];
        zb[t + 128] = buf[cur][row][t + 128];
    }
}

// K7: C2R column IFFT, 16 cols/block. Fold rows 0..128 -> 128-pt complex IFFT.
__global__ __launch_bounds__(256) void k7_c2r(const float2* __restrict__ Z,
                                              float* __restrict__ out) {
    __shared__ float2 S[129][16];
    __shared__ float2 buf[2][128][16];
    const int tid = threadIdx.x;
    const int img = blockIdx.x >> 4;
    const int c0 = (blockIdx.x & 15) * 16;
    const float2* zb = Z + (size_t)img * 33024 + c0;
    for (int idx = tid; idx < 129 * 16; idx += 256) {
        int r = idx >> 4, c = idx & 15;
        S[r][c] = zb[r * 256 + c];
    }
    __syncthreads();
    for (int idx = tid; idx < 128 * 16; idx += 256) {
        int u = idx >> 4, c = idx & 15;
        float2 su = S[u][c];
        float2 s2 = conjf2(S[128 - u][c]);
        float2 e = cadd(su, s2);
        float2 o = csub(su, s2);
        float ws_, wc_;
        __sincosf((float)M_PI * (float)u / 128.f, &ws_, &wc_);
        float2 wo = make_float2(wc_ * o.x - ws_ * o.y, wc_ * o.y + ws_ * o.x);
        buf[0][u][c] = make_float2(e.x - wo.y, e.y + wo.x);  // e + i*wo
    }
    int cur = fft_lds_cols<128, 16, 1, 256>(buf);
    float* ob = out + (size_t)img * 65536 + c0;
    for (int idx = tid; idx < 128 * 16; idx += 256) {
        int n = idx >> 4, c = idx & 15;
        float2 y = buf[cur][n][c];
        ob[(2 * n) * 256 + c] = y.x;
        ob[(2 * n + 1) * 256 + c] = y.y;
    }
}

extern "C" void kernel_launch(void* const* d_in, const int* in_sizes, int n_in,
                              void* d_out, int out_size, void* d_ws, size_t ws_size,
                              hipStream_t stream) {
    const float* x = (const float*)d_in[0];      // (4,64,128,128)
    const float* k = (const float*)d_in[1];      // (4,64,25,25)
    const float* alpha = (const float*)d_in[2];  // (1,64,1,1)
    float* out = (float*)d_out;                  // (4,64,256,256)

    float2* Fx = (float2*)d_ws;           // 256*16384   = 32 MB
    float2* FBh = Fx + 256 * 16384;       // 256*129*256 = 67.6 MB
    float2* Z = FBh + 256 * 33024;        // 256*129*256 = 67.6 MB
    float2* FBtmp = Z + 256 * 33024;      // 256*25*256  = 13.1 MB

    hipLaunchKernelGGL(k1_fft_rows_x, dim3(4096), dim3(256), 0, stream, x, Fx);
    hipLaunchKernelGGL(k2_fft_cols_x, dim3(2048), dim3(256), 0, stream, Fx);
    hipLaunchKernelGGL(k3_fft_rows_k, dim3(6400), dim3(128), 0, stream, k, FBtmp);
    hipLaunchKernelGGL(k4_dft_cols_k, dim3(4096), dim3(256), 0, stream, FBtmp, FBh);
    hipLaunchKernelGGL(k6_fused, dim3(256 * 65), dim3(256), 0, stream, FBh, Fx, alpha, Z);
    hipLaunchKernelGGL(k7_c2r, dim3(4096), dim3(256), 0, stream, Z, out);
}

// Round 5
// 246.733 us; speedup vs baseline: 1.2442x; 1.0266x over previous
//
#include <hip/hip_runtime.h>
#include <math.h>

// Closed-form pipeline with Hermitian (real-output) symmetry:
//   Fx  = fft2_128(x)                 (k1 rows pack-2 real trick, k2 cols)
//   FBh = fft2_256(pad+roll(k)) rows 0..128
//         (k3: row FFT of 25 psf rows; k4: register-resident column DFT)
//   k6 fused: M=(1-S1)/(S2+b) in regs; FX built from FBh rows {um,128-um};
//             row IFFT; write Z rows 0..128 only
//   k7: C2R column IFFT via 128-pt complex FFT fold
// LDS layout rule (R2): float2 column tiles use width 16 (128 B = bank row).
// R3: LDS tiles larger than blockDim need grid-stride loads.
// R4: k4 was LDS-issue bound (450 ds_reads/thread); fix = registers.

static __device__ __forceinline__ float2 cmul(float2 a, float2 b) {
    return make_float2(a.x * b.x - a.y * b.y, a.x * b.y + a.y * b.x);
}
static __device__ __forceinline__ float2 cadd(float2 a, float2 b) {
    return make_float2(a.x + b.x, a.y + b.y);
}
static __device__ __forceinline__ float2 csub(float2 a, float2 b) {
    return make_float2(a.x - b.x, a.y - b.y);
}
static __device__ __forceinline__ float2 conjf2(float2 a) {
    return make_float2(a.x, -a.y);
}

// ---------------- Stockham radix-2 FFT in LDS ----------------
template <int N, int R, int SIGN>
static __device__ __forceinline__ int fft_lds_rows(float2 (&buf)[2][R][N]) {
    constexpr int HB = N / 2;
    const int tid = threadIdx.x;
    const int row = tid / HB;
    const int bt = tid % HB;
    int cur = 0, m = 1, sft = 0;
    for (int l = HB; l >= 1; l >>= 1) {
        __syncthreads();
        const int k = bt & (m - 1);
        const int j = bt >> sft;
        float s, c;
        __sincosf((float)SIGN * (float)M_PI * (float)j / (float)l, &s, &c);
        float2 a = buf[cur][row][bt];
        float2 b = buf[cur][row][bt + HB];
        float2 d = make_float2(a.x - b.x, a.y - b.y);
        float2 wd = make_float2(c * d.x - s * d.y, c * d.y + s * d.x);
        const int o = 2 * bt - k;
        buf[cur ^ 1][row][o] = make_float2(a.x + b.x, a.y + b.y);
        buf[cur ^ 1][row][o + m] = wd;
        cur ^= 1;
        m <<= 1;
        sft++;
    }
    __syncthreads();
    return cur;
}

// Column variant: TC columns (use TC=16 -> conflict-free), FFT along axis 0.
template <int N, int TC, int SIGN, int THREADS>
static __device__ __forceinline__ int fft_lds_cols(float2 (&buf)[2][N][TC]) {
    constexpr int HB = N / 2;
    constexpr int WORK = HB * TC;
    const int tid = threadIdx.x;
    int cur = 0, m = 1, sft = 0;
    for (int l = HB; l >= 1; l >>= 1) {
        __syncthreads();
        for (int w = tid; w < WORK; w += THREADS) {
            const int col = w % TC;
            const int bt = w / TC;
            const int k = bt & (m - 1);
            const int j = bt >> sft;
            float s, c;
            __sincosf((float)SIGN * (float)M_PI * (float)j / (float)l, &s, &c);
            float2 a = buf[cur][bt][col];
            float2 b = buf[cur][bt + HB][col];
            float2 d = make_float2(a.x - b.x, a.y - b.y);
            float2 wd = make_float2(c * d.x - s * d.y, c * d.y + s * d.x);
            const int o = 2 * bt - k;
            buf[cur ^ 1][o][col] = make_float2(a.x + b.x, a.y + b.y);
            buf[cur ^ 1][o + m][col] = wd;
        }
        cur ^= 1;
        m <<= 1;
        sft++;
    }
    __syncthreads();
    return cur;
}

// K1: row FFT of x (N=128) with pack-2: rows (2r,2r+1) as re+i*im of one FFT.
__global__ __launch_bounds__(256) void k1_fft_rows_x(const float* __restrict__ x,
                                                     float2* __restrict__ Fx) {
    __shared__ float2 buf[2][4][128];
    const int tid = threadIdx.x;
    const int row = tid >> 6;   // pair slot 0..3
    const int t = tid & 63;
    const int gpair = blockIdx.x * 4 + row;  // img*64 + pr
    const float* r0 = x + (size_t)gpair * 256;        // row 2*pr (128 floats)
    const float* r1 = r0 + 128;                       // row 2*pr+1
    const float2 a0 = ((const float2*)r0)[t];
    const float2 a1 = ((const float2*)r1)[t];
    buf[0][row][2 * t].x = a0.x;
    buf[0][row][2 * t].y = a1.x;
    buf[0][row][2 * t + 1].x = a0.y;
    buf[0][row][2 * t + 1].y = a1.y;
    int cur = fft_lds_rows<128, 4, -1>(buf);
    float2* d0 = Fx + (size_t)gpair * 256;            // Fx row 2*pr
    float2* d1 = d0 + 128;
    for (int h = 0; h < 2; ++h) {
        int tt = t + h * 64;
        float2 Zt = buf[cur][row][tt];
        float2 Zm = buf[cur][row][(128 - tt) & 127];
        d0[tt] = make_float2(0.5f * (Zt.x + Zm.x), 0.5f * (Zt.y - Zm.y));
        float ax = Zt.x - Zm.x, ay = Zt.y + Zm.y;
        d1[tt] = make_float2(0.5f * ay, -0.5f * ax);
    }
}

// K2: column FFT of Fx (N=128), in place. 16 cols/block (conflict-free).
__global__ __launch_bounds__(256) void k2_fft_cols_x(float2* __restrict__ Fx) {
    __shared__ float2 buf[2][128][16];
    const int tid = threadIdx.x;
    const int img = blockIdx.x >> 3;
    const int c0 = (blockIdx.x & 7) * 16;
    float2* base = Fx + (size_t)img * 16384 + c0;
    for (int it = 0; it < 8; ++it) {
        int idx = it * 256 + tid;
        buf[0][idx >> 4][idx & 15] = base[(idx >> 4) * 128 + (idx & 15)];
    }
    int cur = fft_lds_cols<128, 16, -1, 256>(buf);
    for (int it = 0; it < 8; ++it) {
        int idx = it * 256 + tid;
        base[(idx >> 4) * 128 + (idx & 15)] = buf[cur][idx >> 4][idx & 15];
    }
}

// K3: row FFT of padded+rolled psf (N=256), compact output [img][25][256].
__global__ __launch_bounds__(128) void k3_fft_rows_k(const float* __restrict__ kin,
                                                     float2* __restrict__ FBtmp) {
    __shared__ float2 buf[2][1][256];
    const int tid = threadIdx.x;  // 128
    const int img = blockIdx.x / 25;
    const int lr = blockIdx.x % 25;
    const float* krow = kin + img * 625 + lr * 25;
    for (int h = 0; h < 2; ++h) {
        int v = tid + h * 128;
        int pc = (v + 12) & 255;
        buf[0][0][v] = make_float2(pc < 25 ? krow[pc] : 0.f, 0.f);
    }
    int cur = fft_lds_rows<256, 1, -1>(buf);
    float2* dst = FBtmp + (size_t)img * 6400 + lr * 256;
    dst[tid] = buf[cur][0][tid];
    dst[tid + 128] = buf[cur][0][tid + 128];
}

// K4: register-resident column DFT. Block = image, thread = column j.
// FBh[u][j] = sum_p S[p][j] * W^(u*(p+244)), u=0..128, W=exp(-2*pi*i/256).
// S (25 float2) and twiddles T (25 float2) live in registers; T advances by
// one cmul per u (step constants Wc[p]=W^(p+244)); sincosf reseed every 32 u.
__global__ __launch_bounds__(256) void k4_dft_cols_k(const float2* __restrict__ FBtmp,
                                                     float2* __restrict__ FBh) {
    const int j = threadIdx.x;
    const int img = blockIdx.x;
    const float2* src = FBtmp + (size_t)img * 6400 + j;
    float2 S[25], T[25], Wc[25];
#pragma unroll
    for (int p = 0; p < 25; ++p) S[p] = src[p * 256];
#pragma unroll
    for (int p = 0; p < 25; ++p) {
        int n = (p + 244) & 255;
        float s, c;
        __sincosf(-2.f * (float)M_PI * (float)n / 256.f, &s, &c);
        Wc[p] = make_float2(c, s);
    }
    float2* dst = FBh + (size_t)img * 33024 + j;
    for (int u0 = 0; u0 <= 128; u0 += 32) {
        // reseed T[p] = W^(u0*(p+244)) to kill recurrence drift
#pragma unroll
        for (int p = 0; p < 25; ++p) {
            int n = (u0 * (p + 244)) & 255;
            float s, c;
            __sincosf(-2.f * (float)M_PI * (float)n / 256.f, &s, &c);
            T[p] = make_float2(c, s);
        }
        const int umax = (u0 + 32 <= 128) ? (u0 + 32) : 129;
        for (int u = u0; u < umax; ++u) {
            float2 acc = make_float2(0.f, 0.f);
#pragma unroll
            for (int p = 0; p < 25; ++p) {
                acc.x += T[p].x * S[p].x - T[p].y * S[p].y;
                acc.y += T[p].x * S[p].y + T[p].y * S[p].x;
                float tx = T[p].x * Wc[p].x - T[p].y * Wc[p].y;
                T[p].y = T[p].x * Wc[p].y + T[p].y * Wc[p].x;
                T[p].x = tx;
            }
            dst[(size_t)u * 256] = acc;
        }
    }
}

// K6: fused M + FX build + row IFFT. Row tasks u = 0..128 per image (2/block).
__global__ __launch_bounds__(256) void k6_fused(const float2* __restrict__ FBh,
                                                const float2* __restrict__ Fx,
                                                const float* __restrict__ alpha,
                                                float2* __restrict__ Z) {
    __shared__ float2 buf[2][2][256];
    const int tid = threadIdx.x;
    const int row = tid >> 7;
    const int t = tid & 127;
    const int img = blockIdx.x / 65;
    const int p = blockIdx.x % 65;
    const int u = p * 2 + row;        // 0..129 (129 = dummy duplicate)
    const int uc = (u < 128) ? u : 128;
    const bool wr = (u <= 128);
    const int um = uc & 127;
    const float2* base = FBh + (size_t)img * 33024;

    float2 f00 = base[um * 256 + t];
    float2 f01 = base[um * 256 + t + 128];
    float2 f10, f11;
    if (um == 0) {
        f10 = base[128 * 256 + t];
        f11 = base[128 * 256 + t + 128];
    } else {
        int rs = (128 - um) * 256;
        f10 = conjf2(base[rs + ((256 - t) & 255)]);
        f11 = conjf2(base[rs + (128 - t)]);
    }
    float2 fx = Fx[(size_t)img * 16384 + um * 128 + t];

    float si, ci, sj, cj;
    __sincosf(-(float)M_PI * (float)um / 128.f, &si, &ci);
    __sincosf(-(float)M_PI * (float)t / 128.f, &sj, &cj);
    float2 Di0 = make_float2(1.f + ci, si);
    float2 Di1 = make_float2(1.f - ci, -si);
    float2 Dj0 = make_float2(1.f + cj, sj);
    float2 Dj1 = make_float2(1.f - cj, -sj);
    float2 S1 = cadd(cadd(cmul(cmul(f00, Di0), Dj0), cmul(cmul(f10, Di1), Dj0)),
                     cadd(cmul(cmul(f01, Di0), Dj1), cmul(cmul(f11, Di1), Dj1)));
    S1.x *= 0.25f;
    S1.y *= 0.25f;
    float S2 = 0.25f * (f00.x * f00.x + f00.y * f00.y + f01.x * f01.x + f01.y * f01.y +
                        f10.x * f10.x + f10.y * f10.y + f11.x * f11.x + f11.y * f11.y);
    float b = 1.f / (1.f + __expf(9.f - alpha[img & 63])) + 1e-3f;
    float inv = 1.f / (S2 + b);
    float2 mm = make_float2((1.f - S1.x) * inv, (-S1.y) * inv);

    float2 c0v = (uc < 128) ? f00 : f10;
    float2 c1v = (uc < 128) ? f01 : f11;
    float2 Du = (uc < 128) ? make_float2(1.f + ci, si) : make_float2(1.f - ci, -si);
    float2 Dv0 = make_float2(1.f + cj, sj);
    float2 Dv1 = make_float2(1.f - cj, -sj);
    const float scale = 1.f / 65536.f;
    float2 t0 = cadd(cmul(conjf2(c0v), mm), cmul(Du, Dv0));
    float2 t1 = cadd(cmul(conjf2(c1v), mm), cmul(Du, Dv1));
    float2 FX0 = cmul(fx, t0);
    float2 FX1 = cmul(fx, t1);
    buf[0][row][t] = make_float2(FX0.x * scale, FX0.y * scale);
    buf[0][row][t + 128] = make_float2(FX1.x * scale, FX1.y * scale);
    int cur = fft_lds_rows<256, 2, 1>(buf);
    if (wr) {
        float2* zb = Z + (size_t)img * 33024 + u * 256;
        zb[t] = buf[cur][row][t];
        zb[t + 128] = buf[cur][row][t + 128];
    }
}

// K7: C2R column IFFT, 16 cols/block. Fold rows 0..128 -> 128-pt complex IFFT.
__global__ __launch_bounds__(256) void k7_c2r(const float2* __restrict__ Z,
                                              float* __restrict__ out) {
    __shared__ float2 S[129][16];
    __shared__ float2 buf[2][128][16];
    const int tid = threadIdx.x;
    const int img = blockIdx.x >> 4;
    const int c0 = (blockIdx.x & 15) * 16;
    const float2* zb = Z + (size_t)img * 33024 + c0;
    for (int idx = tid; idx < 129 * 16; idx += 256) {
        int r = idx >> 4, c = idx & 15;
        S[r][c] = zb[r * 256 + c];
    }
    __syncthreads();
    for (int idx = tid; idx < 128 * 16; idx += 256) {
        int u = idx >> 4, c = idx & 15;
        float2 su = S[u][c];
        float2 s2 = conjf2(S[128 - u][c]);
        float2 e = cadd(su, s2);
        float2 o = csub(su, s2);
        float ws_, wc_;
        __sincosf((float)M_PI * (float)u / 128.f, &ws_, &wc_);
        float2 wo = make_float2(wc_ * o.x - ws_ * o.y, wc_ * o.y + ws_ * o.x);
        buf[0][u][c] = make_float2(e.x - wo.y, e.y + wo.x);  // e + i*wo
    }
    int cur = fft_lds_cols<128, 16, 1, 256>(buf);
    float* ob = out + (size_t)img * 65536 + c0;
    for (int idx = tid; idx < 128 * 16; idx += 256) {
        int n = idx >> 4, c = idx & 15;
        float2 y = buf[cur][n][c];
        ob[(2 * n) * 256 + c] = y.x;
        ob[(2 * n + 1) * 256 + c] = y.y;
    }
}

extern "C" void kernel_launch(void* const* d_in, const int* in_sizes, int n_in,
                              void* d_out, int out_size, void* d_ws, size_t ws_size,
                              hipStream_t stream) {
    const float* x = (const float*)d_in[0];      // (4,64,128,128)
    const float* k = (const float*)d_in[1];      // (4,64,25,25)
    const float* alpha = (const float*)d_in[2];  // (1,64,1,1)
    float* out = (float*)d_out;                  // (4,64,256,256)

    float2* Fx = (float2*)d_ws;           // 256*16384   = 32 MB
    float2* FBh = Fx + 256 * 16384;       // 256*129*256 = 67.6 MB
    float2* Z = FBh + 256 * 33024;        // 256*129*256 = 67.6 MB
    float2* FBtmp = Z + 256 * 33024;      // 256*25*256  = 13.1 MB

    hipLaunchKernelGGL(k1_fft_rows_x, dim3(4096), dim3(256), 0, stream, x, Fx);
    hipLaunchKernelGGL(k2_fft_cols_x, dim3(2048), dim3(256), 0, stream, Fx);
    hipLaunchKernelGGL(k3_fft_rows_k, dim3(6400), dim3(128), 0, stream, k, FBtmp);
    hipLaunchKernelGGL(k4_dft_cols_k, dim3(256), dim3(256), 0, stream, FBtmp, FBh);
    hipLaunchKernelGGL(k6_fused, dim3(256 * 65), dim3(256), 0, stream, FBh, Fx, alpha, Z);
    hipLaunchKernelGGL(k7_c2r, dim3(4096), dim3(256), 0, stream, Z, out);
}

// Round 6
// 245.596 us; speedup vs baseline: 1.2500x; 1.0046x over previous
//
#include <hip/hip_runtime.h>
#include <math.h>

// Closed-form pipeline with Hermitian (real-output) symmetry:
//   Fx  = fft2_128(x)                 (k1 rows pack-2 real trick, k2 cols)
//   FBh = fft2_256(pad+roll(k)) rows 0..128
//         (k3: row FFT of 25 psf rows; k4: register-resident column DFT)
//   k6 fused: stage FBh rows {p,128-p} in LDS; M=(1-S1)/(S2+b) in regs;
//             FX rows u=p and u=128-p; row IFFT; write Z rows 0..128
//   k7: C2R column IFFT via 128-pt complex FFT fold
// R2: float2 column tiles use width 16 (128 B = bank row) -> conflict-free.
// R3: LDS tiles larger than blockDim need grid-stride loads.
// R4: k4 LDS-issue bound -> registers.
// R5: k4 spilled at VGPR=128; __launch_bounds__(256,1) lifts the cap
//     (state = 75 float2 ~ 190 VGPR incl. temps).

static __device__ __forceinline__ float2 cmul(float2 a, float2 b) {
    return make_float2(a.x * b.x - a.y * b.y, a.x * b.y + a.y * b.x);
}
static __device__ __forceinline__ float2 cadd(float2 a, float2 b) {
    return make_float2(a.x + b.x, a.y + b.y);
}
static __device__ __forceinline__ float2 csub(float2 a, float2 b) {
    return make_float2(a.x - b.x, a.y - b.y);
}
static __device__ __forceinline__ float2 conjf2(float2 a) {
    return make_float2(a.x, -a.y);
}

// ---------------- Stockham radix-2 FFT in LDS ----------------
template <int N, int R, int SIGN>
static __device__ __forceinline__ int fft_lds_rows(float2 (&buf)[2][R][N]) {
    constexpr int HB = N / 2;
    const int tid = threadIdx.x;
    const int row = tid / HB;
    const int bt = tid % HB;
    int cur = 0, m = 1, sft = 0;
    for (int l = HB; l >= 1; l >>= 1) {
        __syncthreads();
        const int k = bt & (m - 1);
        const int j = bt >> sft;
        float s, c;
        __sincosf((float)SIGN * (float)M_PI * (float)j / (float)l, &s, &c);
        float2 a = buf[cur][row][bt];
        float2 b = buf[cur][row][bt + HB];
        float2 d = make_float2(a.x - b.x, a.y - b.y);
        float2 wd = make_float2(c * d.x - s * d.y, c * d.y + s * d.x);
        const int o = 2 * bt - k;
        buf[cur ^ 1][row][o] = make_float2(a.x + b.x, a.y + b.y);
        buf[cur ^ 1][row][o + m] = wd;
        cur ^= 1;
        m <<= 1;
        sft++;
    }
    __syncthreads();
    return cur;
}

// Column variant: TC columns (TC=16 -> conflict-free), FFT along axis 0.
template <int N, int TC, int SIGN, int THREADS>
static __device__ __forceinline__ int fft_lds_cols(float2 (&buf)[2][N][TC]) {
    constexpr int HB = N / 2;
    constexpr int WORK = HB * TC;
    const int tid = threadIdx.x;
    int cur = 0, m = 1, sft = 0;
    for (int l = HB; l >= 1; l >>= 1) {
        __syncthreads();
        for (int w = tid; w < WORK; w += THREADS) {
            const int col = w % TC;
            const int bt = w / TC;
            const int k = bt & (m - 1);
            const int j = bt >> sft;
            float s, c;
            __sincosf((float)SIGN * (float)M_PI * (float)j / (float)l, &s, &c);
            float2 a = buf[cur][bt][col];
            float2 b = buf[cur][bt + HB][col];
            float2 d = make_float2(a.x - b.x, a.y - b.y);
            float2 wd = make_float2(c * d.x - s * d.y, c * d.y + s * d.x);
            const int o = 2 * bt - k;
            buf[cur ^ 1][o][col] = make_float2(a.x + b.x, a.y + b.y);
            buf[cur ^ 1][o + m][col] = wd;
        }
        cur ^= 1;
        m <<= 1;
        sft++;
    }
    __syncthreads();
    return cur;
}

// K1: row FFT of x (N=128) with pack-2: rows (2r,2r+1) as re+i*im of one FFT.
__global__ __launch_bounds__(256) void k1_fft_rows_x(const float* __restrict__ x,
                                                     float2* __restrict__ Fx) {
    __shared__ float2 buf[2][4][128];
    const int tid = threadIdx.x;
    const int row = tid >> 6;   // pair slot 0..3
    const int t = tid & 63;
    const int gpair = blockIdx.x * 4 + row;  // img*64 + pr
    const float* r0 = x + (size_t)gpair * 256;        // row 2*pr (128 floats)
    const float* r1 = r0 + 128;                       // row 2*pr+1
    const float2 a0 = ((const float2*)r0)[t];
    const float2 a1 = ((const float2*)r1)[t];
    buf[0][row][2 * t].x = a0.x;
    buf[0][row][2 * t].y = a1.x;
    buf[0][row][2 * t + 1].x = a0.y;
    buf[0][row][2 * t + 1].y = a1.y;
    int cur = fft_lds_rows<128, 4, -1>(buf);
    float2* d0 = Fx + (size_t)gpair * 256;            // Fx row 2*pr
    float2* d1 = d0 + 128;
    for (int h = 0; h < 2; ++h) {
        int tt = t + h * 64;
        float2 Zt = buf[cur][row][tt];
        float2 Zm = buf[cur][row][(128 - tt) & 127];
        d0[tt] = make_float2(0.5f * (Zt.x + Zm.x), 0.5f * (Zt.y - Zm.y));
        float ax = Zt.x - Zm.x, ay = Zt.y + Zm.y;
        d1[tt] = make_float2(0.5f * ay, -0.5f * ax);
    }
}

// K2: column FFT of Fx (N=128), in place. 16 cols/block (conflict-free).
__global__ __launch_bounds__(256) void k2_fft_cols_x(float2* __restrict__ Fx) {
    __shared__ float2 buf[2][128][16];
    const int tid = threadIdx.x;
    const int img = blockIdx.x >> 3;
    const int c0 = (blockIdx.x & 7) * 16;
    float2* base = Fx + (size_t)img * 16384 + c0;
    for (int it = 0; it < 8; ++it) {
        int idx = it * 256 + tid;
        buf[0][idx >> 4][idx & 15] = base[(idx >> 4) * 128 + (idx & 15)];
    }
    int cur = fft_lds_cols<128, 16, -1, 256>(buf);
    for (int it = 0; it < 8; ++it) {
        int idx = it * 256 + tid;
        base[(idx >> 4) * 128 + (idx & 15)] = buf[cur][idx >> 4][idx & 15];
    }
}

// K3: row FFT of padded+rolled psf (N=256), compact output [img][25][256].
__global__ __launch_bounds__(128) void k3_fft_rows_k(const float* __restrict__ kin,
                                                     float2* __restrict__ FBtmp) {
    __shared__ float2 buf[2][1][256];
    const int tid = threadIdx.x;  // 128
    const int img = blockIdx.x / 25;
    const int lr = blockIdx.x % 25;
    const float* krow = kin + img * 625 + lr * 25;
    for (int h = 0; h < 2; ++h) {
        int v = tid + h * 128;
        int pc = (v + 12) & 255;
        buf[0][0][v] = make_float2(pc < 25 ? krow[pc] : 0.f, 0.f);
    }
    int cur = fft_lds_rows<256, 1, -1>(buf);
    float2* dst = FBtmp + (size_t)img * 6400 + lr * 256;
    dst[tid] = buf[cur][0][tid];
    dst[tid + 128] = buf[cur][0][tid + 128];
}

// K4: register-resident column DFT. 2 blocks/image (u-halves), thread = col j.
// FBh[u][j] = sum_p S[p][j] * W^(u*(p+244)), u=0..128, W=exp(-2*pi*i/256).
// __launch_bounds__(256,1): allow ~190 VGPR without spill (R5 post-mortem).
__global__ __launch_bounds__(256, 1) void k4_dft_cols_k(const float2* __restrict__ FBtmp,
                                                        float2* __restrict__ FBh) {
    const int j = threadIdx.x;
    const int img = blockIdx.x >> 1;
    const int half = blockIdx.x & 1;
    const int ubeg = half ? 65 : 0;
    const int uend = half ? 129 : 65;  // exclusive
    const float2* src = FBtmp + (size_t)img * 6400 + j;
    float2 S[25], T[25], Wc[25];
#pragma unroll
    for (int p = 0; p < 25; ++p) S[p] = src[p * 256];
#pragma unroll
    for (int p = 0; p < 25; ++p) {
        int n = (p + 244) & 255;
        float s, c;
        __sincosf(-2.f * (float)M_PI * (float)n / 256.f, &s, &c);
        Wc[p] = make_float2(c, s);
    }
    float2* dst = FBh + (size_t)img * 33024 + j;
    for (int u0 = ubeg; u0 < uend; u0 += 32) {
        // reseed T[p] = W^(u0*(p+244)) to kill recurrence drift
#pragma unroll
        for (int p = 0; p < 25; ++p) {
            int n = (u0 * (p + 244)) & 255;
            float s, c;
            __sincosf(-2.f * (float)M_PI * (float)n / 256.f, &s, &c);
            T[p] = make_float2(c, s);
        }
        const int umax = (u0 + 32 < uend) ? (u0 + 32) : uend;
        for (int u = u0; u < umax; ++u) {
            float2 acc = make_float2(0.f, 0.f);
#pragma unroll
            for (int p = 0; p < 25; ++p) {
                acc.x += T[p].x * S[p].x - T[p].y * S[p].y;
                acc.y += T[p].x * S[p].y + T[p].y * S[p].x;
                float tx = T[p].x * Wc[p].x - T[p].y * Wc[p].y;
                T[p].y = T[p].x * Wc[p].y + T[p].y * Wc[p].x;
                T[p].x = tx;
            }
            dst[(size_t)u * 256] = acc;
        }
    }
}

// K6: fused M + FX build + row IFFT, paired rows {p, 128-p} staged in LDS.
// Block = (img, p), p=0..64. Slot row=0 -> u=p, row=1 -> u=128-p.
__global__ __launch_bounds__(256) void k6_fused(const float2* __restrict__ FBh,
                                                const float2* __restrict__ Fx,
                                                const float* __restrict__ alpha,
                                                float2* __restrict__ Z) {
    __shared__ float2 stage[2][256];  // FBh rows p and 128-p
    __shared__ float2 buf[2][2][256];
    const int tid = threadIdx.x;
    const int row = tid >> 7;
    const int t = tid & 127;
    const int img = blockIdx.x / 65;
    const int p = blockIdx.x % 65;
    const int r = p, rp = 128 - p;
    const float2* base = FBh + (size_t)img * 33024;
    stage[0][tid] = base[r * 256 + tid];
    stage[1][tid] = base[rp * 256 + tid];
    __syncthreads();

    const int u = (row == 0) ? p : (128 - p);   // 0..128
    const int um = u & 127;                     // u==128 -> 0
    const int mi = (um == p) ? 0 : 1;           // stage idx holding row um
    const int oi = 1 - mi;                      // stage idx holding row 128-um

    float2 f00 = stage[mi][t];
    float2 f01 = stage[mi][t + 128];
    float2 f10, f11;
    if (um == 0) {  // rows {0,128}: row 128 direct (only p==0)
        f10 = stage[oi][t];
        f11 = stage[oi][t + 128];
    } else {
        f10 = conjf2(stage[oi][(256 - t) & 255]);
        f11 = conjf2(stage[oi][128 - t]);
    }
    float2 fx = Fx[(size_t)img * 16384 + um * 128 + t];

    float si, ci, sj, cj;
    __sincosf(-(float)M_PI * (float)um / 128.f, &si, &ci);
    __sincosf(-(float)M_PI * (float)t / 128.f, &sj, &cj);
    float2 Di0 = make_float2(1.f + ci, si);
    float2 Di1 = make_float2(1.f - ci, -si);
    float2 Dj0 = make_float2(1.f + cj, sj);
    float2 Dj1 = make_float2(1.f - cj, -sj);
    float2 S1 = cadd(cadd(cmul(cmul(f00, Di0), Dj0), cmul(cmul(f10, Di1), Dj0)),
                     cadd(cmul(cmul(f01, Di0), Dj1), cmul(cmul(f11, Di1), Dj1)));
    S1.x *= 0.25f;
    S1.y *= 0.25f;
    float S2 = 0.25f * (f00.x * f00.x + f00.y * f00.y + f01.x * f01.x + f01.y * f01.y +
                        f10.x * f10.x + f10.y * f10.y + f11.x * f11.x + f11.y * f11.y);
    float b = 1.f / (1.f + __expf(9.f - alpha[img & 63])) + 1e-3f;
    float inv = 1.f / (S2 + b);
    float2 mm = make_float2((1.f - S1.x) * inv, (-S1.y) * inv);

    float2 c0v = (u < 128) ? f00 : f10;
    float2 c1v = (u < 128) ? f01 : f11;
    float2 Du = (u < 128) ? make_float2(1.f + ci, si) : make_float2(1.f - ci, -si);
    float2 Dv0 = make_float2(1.f + cj, sj);
    float2 Dv1 = make_float2(1.f - cj, -sj);
    const float scale = 1.f / 65536.f;
    float2 t0 = cadd(cmul(conjf2(c0v), mm), cmul(Du, Dv0));
    float2 t1 = cadd(cmul(conjf2(c1v), mm), cmul(Du, Dv1));
    float2 FX0 = cmul(fx, t0);
    float2 FX1 = cmul(fx, t1);
    buf[0][row][t] = make_float2(FX0.x * scale, FX0.y * scale);
    buf[0][row][t + 128] = make_float2(FX1.x * scale, FX1.y * scale);
    int cur = fft_lds_rows<256, 2, 1>(buf);
    float2* zb = Z + (size_t)img * 33024 + u * 256;  // p=64: both slots u=64, same data
    zb[t] = buf[cur][row][t];
    zb[t + 128] = buf[cur][row][t + 128];
}

// K7: C2R column IFFT, 16 cols/block. Fold rows 0..128 -> 128-pt complex IFFT.
__global__ __launch_bounds__(256) void k7_c2r(const float2* __restrict__ Z,
                                              float* __restrict__ out) {
    __shared__ float2 S[129][16];
    __shared__ float2 buf[2][128][16];
    const int tid = threadIdx.x;
    const int img = blockIdx.x >> 4;
    const int c0 = (blockIdx.x & 15) * 16;
    const float2* zb = Z + (size_t)img * 33024 + c0;
    for (int idx = tid; idx < 129 * 16; idx += 256) {
        int r = idx >> 4, c = idx & 15;
        S[r][c] = zb[r * 256 + c];
    }
    __syncthreads();
    for (int idx = tid; idx < 128 * 16; idx += 256) {
        int u = idx >> 4, c = idx & 15;
        float2 su = S[u][c];
        float2 s2 = conjf2(S[128 - u][c]);
        float2 e = cadd(su, s2);
        float2 o = csub(su, s2);
        float ws_, wc_;
        __sincosf((float)M_PI * (float)u / 128.f, &ws_, &wc_);
        float2 wo = make_float2(wc_ * o.x - ws_ * o.y, wc_ * o.y + ws_ * o.x);
        buf[0][u][c] = make_float2(e.x - wo.y, e.y + wo.x);  // e + i*wo
    }
    int cur = fft_lds_cols<128, 16, 1, 256>(buf);
    float* ob = out + (size_t)img * 65536 + c0;
    for (int idx = tid; idx < 128 * 16; idx += 256) {
        int n = idx >> 4, c = idx & 15;
        float2 y = buf[cur][n][c];
        ob[(2 * n) * 256 + c] = y.x;
        ob[(2 * n + 1) * 256 + c] = y.y;
    }
}

extern "C" void kernel_launch(void* const* d_in, const int* in_sizes, int n_in,
                              void* d_out, int out_size, void* d_ws, size_t ws_size,
                              hipStream_t stream) {
    const float* x = (const float*)d_in[0];      // (4,64,128,128)
    const float* k = (const float*)d_in[1];      // (4,64,25,25)
    const float* alpha = (const float*)d_in[2];  // (1,64,1,1)
    float* out = (float*)d_out;                  // (4,64,256,256)

    float2* Fx = (float2*)d_ws;           // 256*16384   = 32 MB
    float2* FBh = Fx + 256 * 16384;       // 256*129*256 = 67.6 MB
    float2* Z = FBh + 256 * 33024;        // 256*129*256 = 67.6 MB
    float2* FBtmp = Z + 256 * 33024;      // 256*25*256  = 13.1 MB

    hipLaunchKernelGGL(k1_fft_rows_x, dim3(4096), dim3(256), 0, stream, x, Fx);
    hipLaunchKernelGGL(k2_fft_cols_x, dim3(2048), dim3(256), 0, stream, Fx);
    hipLaunchKernelGGL(k3_fft_rows_k, dim3(6400), dim3(128), 0, stream, k, FBtmp);
    hipLaunchKernelGGL(k4_dft_cols_k, dim3(512), dim3(256), 0, stream, FBtmp, FBh);
    hipLaunchKernelGGL(k6_fused, dim3(256 * 65), dim3(256), 0, stream, FBh, Fx, alpha, Z);
    hipLaunchKernelGGL(k7_c2r, dim3(4096), dim3(256), 0, stream, Z, out);
}

// Round 7
// 230.025 us; speedup vs baseline: 1.3346x; 1.0677x over previous
//
#include <hip/hip_runtime.h>
#include <math.h>

// Closed-form pipeline with Hermitian (real-output) symmetry:
//   Fx  = fft2_128(x)                 (k1 rows pack-2 real trick, k2 cols)
//   FBh = fft2_256(pad+roll(k)) rows 0..128
//         (k3: row FFT of 25 psf rows; k4: register-resident column DFT)
//   k6 fused: stage FBh rows {p,128-p} in LDS; M=(1-S1)/(S2+b) in regs;
//             FX rows u=p and u=128-p; row IFFT; write Z rows 0..128
//   k7: C2R column IFFT via 128-pt complex FFT fold
// R2: float2 column tiles use width 16 (128 B = bank row) -> conflict-free.
// R3: LDS tiles larger than blockDim need grid-stride loads.
// R4: k4 LDS-issue bound -> registers.
// R5/R6: 150-float2 state spills at the 128-VGPR cap and __launch_bounds__
//   (256,1) does NOT lift it. Fix: factor T[p]=W^{244u}(W^u)^p -> state is
//   S[25]+tw+E (~75 VGPR), recurrence len 25 reseeded exactly per u.

static __device__ __forceinline__ float2 cmul(float2 a, float2 b) {
    return make_float2(a.x * b.x - a.y * b.y, a.x * b.y + a.y * b.x);
}
static __device__ __forceinline__ float2 cadd(float2 a, float2 b) {
    return make_float2(a.x + b.x, a.y + b.y);
}
static __device__ __forceinline__ float2 csub(float2 a, float2 b) {
    return make_float2(a.x - b.x, a.y - b.y);
}
static __device__ __forceinline__ float2 conjf2(float2 a) {
    return make_float2(a.x, -a.y);
}

// ---------------- Stockham radix-2 FFT in LDS ----------------
template <int N, int R, int SIGN>
static __device__ __forceinline__ int fft_lds_rows(float2 (&buf)[2][R][N]) {
    constexpr int HB = N / 2;
    const int tid = threadIdx.x;
    const int row = tid / HB;
    const int bt = tid % HB;
    int cur = 0, m = 1, sft = 0;
    for (int l = HB; l >= 1; l >>= 1) {
        __syncthreads();
        const int k = bt & (m - 1);
        const int j = bt >> sft;
        float s, c;
        __sincosf((float)SIGN * (float)M_PI * (float)j / (float)l, &s, &c);
        float2 a = buf[cur][row][bt];
        float2 b = buf[cur][row][bt + HB];
        float2 d = make_float2(a.x - b.x, a.y - b.y);
        float2 wd = make_float2(c * d.x - s * d.y, c * d.y + s * d.x);
        const int o = 2 * bt - k;
        buf[cur ^ 1][row][o] = make_float2(a.x + b.x, a.y + b.y);
        buf[cur ^ 1][row][o + m] = wd;
        cur ^= 1;
        m <<= 1;
        sft++;
    }
    __syncthreads();
    return cur;
}

// Column variant: TC columns (TC=16 -> conflict-free), FFT along axis 0.
template <int N, int TC, int SIGN, int THREADS>
static __device__ __forceinline__ int fft_lds_cols(float2 (&buf)[2][N][TC]) {
    constexpr int HB = N / 2;
    constexpr int WORK = HB * TC;
    const int tid = threadIdx.x;
    int cur = 0, m = 1, sft = 0;
    for (int l = HB; l >= 1; l >>= 1) {
        __syncthreads();
        for (int w = tid; w < WORK; w += THREADS) {
            const int col = w % TC;
            const int bt = w / TC;
            const int k = bt & (m - 1);
            const int j = bt >> sft;
            float s, c;
            __sincosf((float)SIGN * (float)M_PI * (float)j / (float)l, &s, &c);
            float2 a = buf[cur][bt][col];
            float2 b = buf[cur][bt + HB][col];
            float2 d = make_float2(a.x - b.x, a.y - b.y);
            float2 wd = make_float2(c * d.x - s * d.y, c * d.y + s * d.x);
            const int o = 2 * bt - k;
            buf[cur ^ 1][o][col] = make_float2(a.x + b.x, a.y + b.y);
            buf[cur ^ 1][o + m][col] = wd;
        }
        cur ^= 1;
        m <<= 1;
        sft++;
    }
    __syncthreads();
    return cur;
}

// K1: row FFT of x (N=128) with pack-2: rows (2r,2r+1) as re+i*im of one FFT.
__global__ __launch_bounds__(256) void k1_fft_rows_x(const float* __restrict__ x,
                                                     float2* __restrict__ Fx) {
    __shared__ float2 buf[2][4][128];
    const int tid = threadIdx.x;
    const int row = tid >> 6;   // pair slot 0..3
    const int t = tid & 63;
    const int gpair = blockIdx.x * 4 + row;  // img*64 + pr
    const float* r0 = x + (size_t)gpair * 256;        // row 2*pr (128 floats)
    const float* r1 = r0 + 128;                       // row 2*pr+1
    const float2 a0 = ((const float2*)r0)[t];
    const float2 a1 = ((const float2*)r1)[t];
    buf[0][row][2 * t].x = a0.x;
    buf[0][row][2 * t].y = a1.x;
    buf[0][row][2 * t + 1].x = a0.y;
    buf[0][row][2 * t + 1].y = a1.y;
    int cur = fft_lds_rows<128, 4, -1>(buf);
    float2* d0 = Fx + (size_t)gpair * 256;            // Fx row 2*pr
    float2* d1 = d0 + 128;
    for (int h = 0; h < 2; ++h) {
        int tt = t + h * 64;
        float2 Zt = buf[cur][row][tt];
        float2 Zm = buf[cur][row][(128 - tt) & 127];
        d0[tt] = make_float2(0.5f * (Zt.x + Zm.x), 0.5f * (Zt.y - Zm.y));
        float ax = Zt.x - Zm.x, ay = Zt.y + Zm.y;
        d1[tt] = make_float2(0.5f * ay, -0.5f * ax);
    }
}

// K2: column FFT of Fx (N=128), in place. 16 cols/block (conflict-free).
__global__ __launch_bounds__(256) void k2_fft_cols_x(float2* __restrict__ Fx) {
    __shared__ float2 buf[2][128][16];
    const int tid = threadIdx.x;
    const int img = blockIdx.x >> 3;
    const int c0 = (blockIdx.x & 7) * 16;
    float2* base = Fx + (size_t)img * 16384 + c0;
    for (int it = 0; it < 8; ++it) {
        int idx = it * 256 + tid;
        buf[0][idx >> 4][idx & 15] = base[(idx >> 4) * 128 + (idx & 15)];
    }
    int cur = fft_lds_cols<128, 16, -1, 256>(buf);
    for (int it = 0; it < 8; ++it) {
        int idx = it * 256 + tid;
        base[(idx >> 4) * 128 + (idx & 15)] = buf[cur][idx >> 4][idx & 15];
    }
}

// K3: row FFT of padded+rolled psf (N=256), compact output [img][25][256].
__global__ __launch_bounds__(128) void k3_fft_rows_k(const float* __restrict__ kin,
                                                     float2* __restrict__ FBtmp) {
    __shared__ float2 buf[2][1][256];
    const int tid = threadIdx.x;  // 128
    const int img = blockIdx.x / 25;
    const int lr = blockIdx.x % 25;
    const float* krow = kin + img * 625 + lr * 25;
    for (int h = 0; h < 2; ++h) {
        int v = tid + h * 128;
        int pc = (v + 12) & 255;
        buf[0][0][v] = make_float2(pc < 25 ? krow[pc] : 0.f, 0.f);
    }
    int cur = fft_lds_rows<256, 1, -1>(buf);
    float2* dst = FBtmp + (size_t)img * 6400 + lr * 256;
    dst[tid] = buf[cur][0][tid];
    dst[tid + 128] = buf[cur][0][tid + 128];
}

// K4: register-resident column DFT, low-state form (R6 post-mortem).
// FBh[u][j] = sum_p S[p][j] * W^(u*(p+244)) = W^{244u} * sum_p S[p] (W^u)^p.
// Per u: seed tw=W^{244u}, step E=W^u (2 sincosf), advance tw by cmul per p.
// State: S[25] + tw/E/acc ~ 75 VGPR -> no spill. 4 u-quarters per image.
__global__ __launch_bounds__(256) void k4_dft_cols_k(const float2* __restrict__ FBtmp,
                                                     float2* __restrict__ FBh) {
    const int j = threadIdx.x;
    const int img = blockIdx.x >> 2;
    const int q = blockIdx.x & 3;
    const int ubeg = q * 33;
    const int uend = (ubeg + 33 < 129) ? (ubeg + 33) : 129;
    const float2* src = FBtmp + (size_t)img * 6400 + j;
    float2 S[25];
#pragma unroll
    for (int p = 0; p < 25; ++p) S[p] = src[p * 256];
    float2* dst = FBh + (size_t)img * 33024 + j;
    const float k2pi = -2.f * (float)M_PI / 256.f;
    for (int u = ubeg; u < uend; ++u) {
        float sb, cb, se, ce;
        __sincosf(k2pi * (float)((244 * u) & 255), &sb, &cb);
        __sincosf(k2pi * (float)(u & 255), &se, &ce);
        float2 tw = make_float2(cb, sb);
        const float2 E = make_float2(ce, se);
        float2 acc = make_float2(0.f, 0.f);
#pragma unroll
        for (int p = 0; p < 25; ++p) {
            acc.x += tw.x * S[p].x - tw.y * S[p].y;
            acc.y += tw.x * S[p].y + tw.y * S[p].x;
            float tx = tw.x * E.x - tw.y * E.y;
            tw.y = tw.x * E.y + tw.y * E.x;
            tw.x = tx;
        }
        dst[(size_t)u * 256] = acc;
    }
}

// K6: fused M + FX build + row IFFT, paired rows {p, 128-p} staged in LDS.
// Block = (img, p), p=0..64. Slot row=0 -> u=p, row=1 -> u=128-p.
__global__ __launch_bounds__(256) void k6_fused(const float2* __restrict__ FBh,
                                                const float2* __restrict__ Fx,
                                                const float* __restrict__ alpha,
                                                float2* __restrict__ Z) {
    __shared__ float2 stage[2][256];  // FBh rows p and 128-p
    __shared__ float2 buf[2][2][256];
    const int tid = threadIdx.x;
    const int row = tid >> 7;
    const int t = tid & 127;
    const int img = blockIdx.x / 65;
    const int p = blockIdx.x % 65;
    const int r = p, rp = 128 - p;
    const float2* base = FBh + (size_t)img * 33024;
    stage[0][tid] = base[r * 256 + tid];
    stage[1][tid] = base[rp * 256 + tid];
    __syncthreads();

    const int u = (row == 0) ? p : (128 - p);   // 0..128
    const int um = u & 127;                     // u==128 -> 0
    const int mi = (um == p) ? 0 : 1;           // stage idx holding row um
    const int oi = 1 - mi;                      // stage idx holding row 128-um

    float2 f00 = stage[mi][t];
    float2 f01 = stage[mi][t + 128];
    float2 f10, f11;
    if (um == 0) {  // rows {0,128}: row 128 direct (only p==0)
        f10 = stage[oi][t];
        f11 = stage[oi][t + 128];
    } else {
        f10 = conjf2(stage[oi][(256 - t) & 255]);
        f11 = conjf2(stage[oi][128 - t]);
    }
    float2 fx = Fx[(size_t)img * 16384 + um * 128 + t];

    float si, ci, sj, cj;
    __sincosf(-(float)M_PI * (float)um / 128.f, &si, &ci);
    __sincosf(-(float)M_PI * (float)t / 128.f, &sj, &cj);
    float2 Di0 = make_float2(1.f + ci, si);
    float2 Di1 = make_float2(1.f - ci, -si);
    float2 Dj0 = make_float2(1.f + cj, sj);
    float2 Dj1 = make_float2(1.f - cj, -sj);
    float2 S1 = cadd(cadd(cmul(cmul(f00, Di0), Dj0), cmul(cmul(f10, Di1), Dj0)),
                     cadd(cmul(cmul(f01, Di0), Dj1), cmul(cmul(f11, Di1), Dj1)));
    S1.x *= 0.25f;
    S1.y *= 0.25f;
    float S2 = 0.25f * (f00.x * f00.x + f00.y * f00.y + f01.x * f01.x + f01.y * f01.y +
                        f10.x * f10.x + f10.y * f10.y + f11.x * f11.x + f11.y * f11.y);
    float b = 1.f / (1.f + __expf(9.f - alpha[img & 63])) + 1e-3f;
    float inv = 1.f / (S2 + b);
    float2 mm = make_float2((1.f - S1.x) * inv, (-S1.y) * inv);

    float2 c0v = (u < 128) ? f00 : f10;
    float2 c1v = (u < 128) ? f01 : f11;
    float2 Du = (u < 128) ? make_float2(1.f + ci, si) : make_float2(1.f - ci, -si);
    float2 Dv0 = make_float2(1.f + cj, sj);
    float2 Dv1 = make_float2(1.f - cj, -sj);
    const float scale = 1.f / 65536.f;
    float2 t0 = cadd(cmul(conjf2(c0v), mm), cmul(Du, Dv0));
    float2 t1 = cadd(cmul(conjf2(c1v), mm), cmul(Du, Dv1));
    float2 FX0 = cmul(fx, t0);
    float2 FX1 = cmul(fx, t1);
    buf[0][row][t] = make_float2(FX0.x * scale, FX0.y * scale);
    buf[0][row][t + 128] = make_float2(FX1.x * scale, FX1.y * scale);
    int cur = fft_lds_rows<256, 2, 1>(buf);
    float2* zb = Z + (size_t)img * 33024 + u * 256;  // p=64: both slots u=64, same data
    zb[t] = buf[cur][row][t];
    zb[t + 128] = buf[cur][row][t + 128];
}

// K7: C2R column IFFT, 16 cols/block. Fold rows 0..128 -> 128-pt complex IFFT.
__global__ __launch_bounds__(256) void k7_c2r(const float2* __restrict__ Z,
                                              float* __restrict__ out) {
    __shared__ float2 S[129][16];
    __shared__ float2 buf[2][128][16];
    const int tid = threadIdx.x;
    const int img = blockIdx.x >> 4;
    const int c0 = (blockIdx.x & 15) * 16;
    const float2* zb = Z + (size_t)img * 33024 + c0;
    for (int idx = tid; idx < 129 * 16; idx += 256) {
        int r = idx >> 4, c = idx & 15;
        S[r][c] = zb[r * 256 + c];
    }
    __syncthreads();
    for (int idx = tid; idx < 128 * 16; idx += 256) {
        int u = idx >> 4, c = idx & 15;
        float2 su = S[u][c];
        float2 s2 = conjf2(S[128 - u][c]);
        float2 e = cadd(su, s2);
        float2 o = csub(su, s2);
        float ws_, wc_;
        __sincosf((float)M_PI * (float)u / 128.f, &ws_, &wc_);
        float2 wo = make_float2(wc_ * o.x - ws_ * o.y, wc_ * o.y + ws_ * o.x);
        buf[0][u][c] = make_float2(e.x - wo.y, e.y + wo.x);  // e + i*wo
    }
    int cur = fft_lds_cols<128, 16, 1, 256>(buf);
    float* ob = out + (size_t)img * 65536 + c0;
    for (int idx = tid; idx < 128 * 16; idx += 256) {
        int n = idx >> 4, c = idx & 15;
        float2 y = buf[cur][n][c];
        ob[(2 * n) * 256 + c] = y.x;
        ob[(2 * n + 1) * 256 + c] = y.y;
    }
}

extern "C" void kernel_launch(void* const* d_in, const int* in_sizes, int n_in,
                              void* d_out, int out_size, void* d_ws, size_t ws_size,
                              hipStream_t stream) {
    const float* x = (const float*)d_in[0];      // (4,64,128,128)
    const float* k = (const float*)d_in[1];      // (4,64,25,25)
    const float* alpha = (const float*)d_in[2];  // (1,64,1,1)
    float* out = (float*)d_out;                  // (4,64,256,256)

    float2* Fx = (float2*)d_ws;           // 256*16384   = 32 MB
    float2* FBh = Fx + 256 * 16384;       // 256*129*256 = 67.6 MB
    float2* Z = FBh + 256 * 33024;        // 256*129*256 = 67.6 MB
    float2* FBtmp = Z + 256 * 33024;      // 256*25*256  = 13.1 MB

    hipLaunchKernelGGL(k1_fft_rows_x, dim3(4096), dim3(256), 0, stream, x, Fx);
    hipLaunchKernelGGL(k2_fft_cols_x, dim3(2048), dim3(256), 0, stream, Fx);
    hipLaunchKernelGGL(k3_fft_rows_k, dim3(6400), dim3(128), 0, stream, k, FBtmp);
    hipLaunchKernelGGL(k4_dft_cols_k, dim3(1024), dim3(256), 0, stream, FBtmp, FBh);
    hipLaunchKernelGGL(k6_fused, dim3(256 * 65), dim3(256), 0, stream, FBh, Fx, alpha, Z);
    hipLaunchKernelGGL(k7_c2r, dim3(4096), dim3(256), 0, stream, Z, out);
}